// Round 11
// baseline (1507.516 us; speedup 1.0000x reference)
//
#include <hip/hip_runtime.h>
#include <math.h>
#include <stdint.h>

typedef _Float16 f16;
typedef _Float16 f16x8 __attribute__((ext_vector_type(8)));
typedef float f32x4 __attribute__((ext_vector_type(4)));
typedef unsigned short u16;
typedef u16 u16x8 __attribute__((ext_vector_type(8)));

#define HID 256
#define NS1C 100              // layer-1 conv K-steps: 25 taps x 4 channel-groups
#define NS2 8                 // 256/32
#define NPX 65536
#define BPX 64
#define NBLK (NPX/BPX)        // 1024
#define SPAD 260              // padded image dim (2-px border)
#define NSP (SPAD*SPAD)       // 67600 padded spatial positions

// ws layout (bytes)
#define OFF_W1C 0
#define SZ_W1C  ((size_t)NS1C*32768)         // 3,276,800
#define OFF_W2  SZ_W1C
#define SZ_W2   ((size_t)NS2*32768)
#define OFF_W3  (OFF_W2+SZ_W2)
#define OFF_XH  ((size_t)4194304)            // 4 MB
#define SZ_XP   ((size_t)NSP*128*2)          // 17,305,600
#define OFF_XL  (OFF_XH + SZ_XP)
#define OFF_HH  (OFF_XL + SZ_XP)             // 38,805,504
#define SZ_HP   ((size_t)NPX*HID*2)          // 33,554,432
#define OFF_HL  (OFF_HH + SZ_HP)             // total ~106 MB (< ws, proven r9)

__device__ inline void split2(float v, u16& h, u16& l){
  f16 hv = (f16)v;
  f16 lv = (f16)(v - (float)hv);
  h = __builtin_bit_cast(u16, hv);
  l = __builtin_bit_cast(u16, lv);
}

// ---------------------------------------------------------------------------
// prep_w: W (fp32 [K][256]) -> fp16 hi/lo MFMA-fragment units (proven layout):
//   unit(s, w, nf, split, lane): 8 f16, j -> W[s*32+(lane>>4)*8+j][w*64+nf*16+(lane&15)]
//   unit offset = (((s*4 + w)*4 + nf)*2 + split)*64 + lane
// ---------------------------------------------------------------------------
__global__ void prep_w(const float* __restrict__ W, int Kact, int nStages,
                       u16* __restrict__ outp){
  int t = blockIdx.x*256 + threadIdx.x;
  if (t >= nStages*1024) return;
  int s = t >> 10, r = t & 1023;
  int w = r >> 8, nf = (r >> 6) & 3, l = r & 63;
  int col = w*64 + nf*16 + (l & 15);
  int kb  = s*32 + (l >> 4)*8;
  u16x8 hv, lv;
  #pragma unroll
  for (int j = 0; j < 8; ++j){
    int k = kb + j;
    float v = (k < Kact) ? W[(size_t)k*HID + col] : 0.f;
    u16 h, lo; split2(v, h, lo);
    hv[j] = h; lv[j] = lo;
  }
  size_t U0 = ((((size_t)s*4 + w)*4 + nf)*2 + 0)*64 + l;
  *(u16x8*)(outp + U0*8)      = hv;
  *(u16x8*)(outp + (U0+64)*8) = lv;
}

// prep_w1c: W1 rows 0..3199 tap-major (step s: tap=s>>2, cg=s&3; c=cg*32+..., k=c*25+tap)
__global__ void prep_w1c(const float* __restrict__ W1, u16* __restrict__ outp){
  int t = blockIdx.x*256 + threadIdx.x;
  if (t >= NS1C*1024) return;
  int s = t >> 10, r = t & 1023;
  int w = r >> 8, nf = (r >> 6) & 3, l = r & 63;
  int col = w*64 + nf*16 + (l & 15);
  int tap = s >> 2, cg = s & 3;
  int cb  = cg*32 + (l >> 4)*8;
  u16x8 hv, lv;
  #pragma unroll
  for (int j = 0; j < 8; ++j){
    int c = cb + j;
    float v = W1[(size_t)(c*25 + tap)*HID + col];
    u16 h, lo; split2(v, h, lo);
    hv[j] = h; lv[j] = lo;
  }
  size_t U0 = ((((size_t)s*4 + w)*4 + nf)*2 + 0)*64 + l;
  *(u16x8*)(outp + U0*8)      = hv;
  *(u16x8*)(outp + (U0+64)*8) = lv;
}

// ---------------------------------------------------------------------------
// prep_x: zero-padded channel-interleaved planes.
//   Xh[sp][c] = f16-hi(xi[c][sp-interior]), Xl = f16-lo; border rows/cols = 0.
//   sp = py*260 + px (padded coords); interior py,px in [2,258).
// Reads coalesced (fixed c, consecutive sp across lanes); writes 16B/thread.
// ---------------------------------------------------------------------------
__global__ __launch_bounds__(256)
void prep_x(const float* __restrict__ xi, u16* __restrict__ Xh, u16* __restrict__ Xl){
  int sp = blockIdx.x*256 + threadIdx.x;
  if (sp >= NSP) return;
  int py = sp / SPAD;
  int px = sp - py*SPAD;
  bool inb = (py >= 2) & (py < 258) & (px >= 2) & (px < 258);
  const float* xin = xi + ((size_t)(py-2)<<8) + (px-2);
  #pragma unroll 4
  for (int cg = 0; cg < 16; ++cg){
    u16x8 hv, lv;
    #pragma unroll
    for (int j = 0; j < 8; ++j){
      float v = inb ? xin[((size_t)(cg*8 + j))<<16] : 0.f;
      u16 h, l; split2(v, h, l); hv[j] = h; lv[j] = l;
    }
    *(u16x8*)(Xh + (size_t)sp*128 + cg*8) = hv;
    *(u16x8*)(Xl + (size_t)sp*128 + cg*8) = lv;
  }
}

// ---------------------------------------------------------------------------
// Unified GEMM layer, ALL staging via global_load_lds (zero reg round-trip).
// 64px x 256col block, 4 waves, dbuf A(2x8KB)+B(2x32KB) = 80 KB -> 2 blocks/CU.
// Per thread per step: 2 A-DMA + 8 B-DMA; per wave: 16 ds_read_b128 + 48 MFMA.
// MODE 0: A = conv taps of Xh/Xl (padded, no predication), nt=100,
//         epilogue adds exact-f32 coords + bias, writes Hh/Hl.
// MODE 1: A = Hh/Hl, nt=8, writes Hh/Hl.
// MODE 2: A = Hh/Hl, nt=8, fused layer-4 tail -> out.
// ---------------------------------------------------------------------------
template<int MODE>
__global__ __launch_bounds__(256, 2)
void gemm(const u16* __restrict__ Ah, const u16* __restrict__ Al,
          const u16* __restrict__ Wp, const float* __restrict__ W1,
          const float* __restrict__ b, u16* __restrict__ Hh, u16* __restrict__ Hl,
          const float* __restrict__ W4, const float* __restrict__ b4,
          float* __restrict__ out, int nt)
{
  __shared__ __align__(16) u16 Ab[2][4096];   // 8 KB/buf: [mfb(4)][split(2)][unit(64)][8]
  __shared__ __align__(16) u16 Bb[2][16384];  // 32 KB/buf

  const int tid  = threadIdx.x;
  const int lane = tid & 63;
  const int wv   = tid >> 6;

  int bid = blockIdx.x;
  bid = (bid & 7)*(NBLK/8) + (bid >> 3);   // XCD-chunked swizzle (1024%8==0)
  const int pxb = bid * BPX;
  const int y   = pxb >> 8;
  const int x0  = pxb & 255;

  f32x4 acc[4][4];
  #pragma unroll
  for (int a=0;a<4;a++)
    #pragma unroll
    for (int b2=0;b2<4;b2++) acc[a][b2] = f32x4{0.f,0.f,0.f,0.f};

  // A-stage: wave wv owns mfb=wv; lane l = unit l (px = wv*16+(l&15), koct = l>>4).
#define A_STAGE(S, BUF) do { \
    size_t off; \
    if (MODE == 0){ \
      const int tap = (S) >> 2, cg = (S) & 3; \
      const int dy = tap/5, dx = tap - 5*dy; \
      const int sp = (y + dy)*SPAD + (x0 + dx) + wv*16 + (lane & 15); \
      off = (size_t)sp*128 + cg*32 + (lane >> 4)*8; \
    } else { \
      const int px = pxb + wv*16 + (lane & 15); \
      off = (size_t)px*HID + (S)*32 + (lane >> 4)*8; \
    } \
    __builtin_amdgcn_global_load_lds( \
      (const __attribute__((address_space(1))) uint32_t*)(Ah + off), \
      (__attribute__((address_space(3))) uint32_t*)((char*)&Ab[BUF][0] + (wv*2+0)*1024), \
      16, 0, 0); \
    __builtin_amdgcn_global_load_lds( \
      (const __attribute__((address_space(1))) uint32_t*)(Al + off), \
      (__attribute__((address_space(3))) uint32_t*)((char*)&Ab[BUF][0] + (wv*2+1)*1024), \
      16, 0, 0); \
  } while(0)

#define B_STAGE(S, BUF) do { \
    const char* _src = (const char*)Wp + (size_t)(S)*32768 + wv*8192 + lane*16; \
    char* _dst = (char*)&Bb[BUF][0] + wv*8192; \
    _Pragma("unroll") \
    for (int i=0;i<8;++i) \
      __builtin_amdgcn_global_load_lds( \
        (const __attribute__((address_space(1))) uint32_t*)(_src + i*1024), \
        (__attribute__((address_space(3))) uint32_t*)(_dst + i*1024), 16, 0, 0); \
  } while(0)

  A_STAGE(0, 0);
  B_STAGE(0, 0);
  __syncthreads();

  int cur = 0;
  for (int t = 0; t < nt; ++t){
    const int nxt = cur ^ 1;
    if (t+1 < nt){
      A_STAGE(t+1, nxt);      // DMA, drained by end-of-step barrier
      B_STAGE(t+1, nxt);
    }
    f16x8 ahf[4], alf[4];
    #pragma unroll
    for (int mf=0;mf<4;++mf){
      ahf[mf] = *(const f16x8*)(&Ab[cur][((size_t)((mf*2+0)*64 + lane))*8]);
      alf[mf] = *(const f16x8*)(&Ab[cur][((size_t)((mf*2+1)*64 + lane))*8]);
    }
    __builtin_amdgcn_s_setprio(1);
    #pragma unroll
    for (int nf=0;nf<4;++nf){
      f16x8 bh = *(const f16x8*)(&Bb[cur][((size_t)(((wv*4+nf)*2+0)*64 + lane))*8]);
      f16x8 bl = *(const f16x8*)(&Bb[cur][((size_t)(((wv*4+nf)*2+1)*64 + lane))*8]);
      #pragma unroll
      for (int mf=0;mf<4;++mf){
        acc[mf][nf] = __builtin_amdgcn_mfma_f32_16x16x32_f16(ahf[mf], bh, acc[mf][nf], 0,0,0);
        acc[mf][nf] = __builtin_amdgcn_mfma_f32_16x16x32_f16(alf[mf], bh, acc[mf][nf], 0,0,0);
        acc[mf][nf] = __builtin_amdgcn_mfma_f32_16x16x32_f16(ahf[mf], bl, acc[mf][nf], 0,0,0);
      }
    }
    __builtin_amdgcn_s_setprio(0);
    __syncthreads();            // drains vmcnt(0): buf[nxt] ready, buf[cur] free
    cur = nxt;
  }

  float bcol[4];
  #pragma unroll
  for (int nf=0;nf<4;++nf) bcol[nf] = b[wv*64 + nf*16 + (lane&15)];

  if (MODE == 0){
    // exact-f32 coords + bias, h = sin(30 z) -> Hh/Hl planes
    float wyv[4], wxv[4];
    #pragma unroll
    for (int nf=0;nf<4;++nf){
      int col = wv*64 + nf*16 + (lane&15);
      wyv[nf] = W1[(size_t)3200*HID + col];
      wxv[nf] = W1[(size_t)3201*HID + col];
    }
    const float gy = -1.f + (2.f/255.f)*(float)y;
    #pragma unroll
    for (int mf=0;mf<4;++mf)
      #pragma unroll
      for (int nf=0;nf<4;++nf)
        #pragma unroll
        for (int j=0;j<4;++j){
          int row = mf*16 + (lane>>4)*4 + j;
          float gx = -1.f + (2.f/255.f)*(float)(x0 + row);
          float z = acc[mf][nf][j] + bcol[nf] + gy*wyv[nf] + gx*wxv[nf];
          float h = sinf(30.f*z);
          u16 hh,ll; split2(h,hh,ll);
          int col = wv*64 + nf*16 + (lane&15);
          size_t o = (size_t)(pxb+row)*HID + col;
          Hh[o] = hh; Hl[o] = ll;
        }
  } else if (MODE == 1){
    #pragma unroll
    for (int mf=0;mf<4;++mf)
      #pragma unroll
      for (int nf=0;nf<4;++nf)
        #pragma unroll
        for (int j=0;j<4;++j){
          float z = acc[mf][nf][j] + bcol[nf];
          float h = sinf(30.f*z);
          u16 hh,ll; split2(h,hh,ll);
          int row = mf*16 + (lane>>4)*4 + j;
          int col = wv*64 + nf*16 + (lane&15);
          size_t o = (size_t)(pxb+row)*HID + col;
          Hh[o] = hh; Hl[o] = ll;
        }
  } else {
    float (*red)[64][3] = (float(*)[64][3])(void*)&Ab[0][0];  // overlay, buffers dead
    float w4v[4][3];
    #pragma unroll
    for (int nf=0;nf<4;++nf){
      int col = wv*64 + nf*16 + (lane&15);
      w4v[nf][0]=W4[col*3+0]; w4v[nf][1]=W4[col*3+1]; w4v[nf][2]=W4[col*3+2];
    }
    #pragma unroll
    for (int mf=0;mf<4;++mf)
      #pragma unroll
      for (int j=0;j<4;++j){
        float s0=0.f,s1=0.f,s2=0.f;
        #pragma unroll
        for (int nf=0;nf<4;++nf){
          float h = sinf(30.f*(acc[mf][nf][j] + bcol[nf]));
          s0 += h*w4v[nf][0]; s1 += h*w4v[nf][1]; s2 += h*w4v[nf][2];
        }
        #pragma unroll
        for (int m=1;m<16;m<<=1){
          s0 += __shfl_xor(s0, m);
          s1 += __shfl_xor(s1, m);
          s2 += __shfl_xor(s2, m);
        }
        if ((lane & 15) == 0){
          int row = mf*16 + (lane>>4)*4 + j;
          red[wv][row][0]=s0; red[wv][row][1]=s1; red[wv][row][2]=s2;
        }
      }
    __syncthreads();
    if (tid < 192){
      int px = tid & 63, c = tid >> 6;
      float v = red[0][px][c]+red[1][px][c]+red[2][px][c]+red[3][px][c] + b4[c];
      out[(size_t)c*NPX + pxb + px] = v;
    }
  }
#undef A_STAGE
#undef B_STAGE
}

// ---------------------------------------------------------------------------
extern "C" void kernel_launch(void* const* d_in, const int* in_sizes, int n_in,
                              void* d_out, int out_size, void* d_ws, size_t ws_size,
                              hipStream_t stream) {
  const float* xi = (const float*)d_in[0];
  const float* W1 = (const float*)d_in[1];
  const float* b1 = (const float*)d_in[2];
  const float* W2 = (const float*)d_in[3];
  const float* b2 = (const float*)d_in[4];
  const float* W3 = (const float*)d_in[5];
  const float* b3 = (const float*)d_in[6];
  const float* W4 = (const float*)d_in[7];
  const float* b4 = (const float*)d_in[8];
  float* out = (float*)d_out;

  char* ws = (char*)d_ws;
  u16* W1c = (u16*)(ws + OFF_W1C);
  u16* W2p = (u16*)(ws + OFF_W2);
  u16* W3p = (u16*)(ws + OFF_W3);
  u16* Xh  = (u16*)(ws + OFF_XH);
  u16* Xl  = (u16*)(ws + OFF_XL);
  u16* Hh  = (u16*)(ws + OFF_HH);
  u16* Hl  = (u16*)(ws + OFF_HL);

  prep_w1c<<<NS1C*4, 256, 0, stream>>>(W1, W1c);
  prep_w<<<NS2*4, 256, 0, stream>>>(W2, HID, NS2, W2p);
  prep_w<<<NS2*4, 256, 0, stream>>>(W3, HID, NS2, W3p);
  prep_x<<<(NSP + 255)/256, 256, 0, stream>>>(xi, Xh, Xl);

  dim3 grid(NBLK), block(256);
  gemm<0><<<grid, block, 0, stream>>>(Xh, Xl, W1c, W1, b1, Hh, Hl,
                                      nullptr, nullptr, nullptr, NS1C);
  gemm<1><<<grid, block, 0, stream>>>(Hh, Hl, W2p, nullptr, b2, Hh, Hl,
                                      nullptr, nullptr, nullptr, NS2);
  gemm<2><<<grid, block, 0, stream>>>(Hh, Hl, W3p, nullptr, b3, nullptr, nullptr,
                                      W4, b4, out, NS2);
}

// Round 12
// 562.698 us; speedup vs baseline: 2.6791x; 2.6791x over previous
//
#include <hip/hip_runtime.h>
#include <math.h>
#include <stdint.h>

typedef _Float16 f16;
typedef _Float16 f16x8 __attribute__((ext_vector_type(8)));
typedef float f32x4 __attribute__((ext_vector_type(4)));
typedef unsigned short u16;
typedef u16 u16x8 __attribute__((ext_vector_type(8)));

#define HID 256
#define NS1C 100              // layer-1 conv K-steps: 25 taps x 4 channel-groups
#define NS2 8                 // 256/32
#define NPX 65536
#define BPXG 128              // pixels per block (all GEMM layers)
#define NBG (NPX/BPXG)        // 512 blocks -> 2 rounds at 1 block/CU
#define SPAD 260
#define NSP (SPAD*SPAD)

// ws layout (bytes) — same as r11 (~106 MB, fits; proven r9)
#define OFF_W1C 0
#define SZ_W1C  ((size_t)NS1C*32768)
#define OFF_W2  SZ_W1C
#define SZ_W2   ((size_t)NS2*32768)
#define OFF_W3  (OFF_W2+SZ_W2)
#define OFF_XH  ((size_t)4194304)
#define SZ_XP   ((size_t)NSP*128*2)
#define OFF_XL  (OFF_XH + SZ_XP)
#define OFF_HH  (OFF_XL + SZ_XP)
#define SZ_HP   ((size_t)NPX*HID*2)
#define OFF_HL  (OFF_HH + SZ_HP)

__device__ inline void split2(float v, u16& h, u16& l){
  f16 hv = (f16)v;
  f16 lv = (f16)(v - (float)hv);
  h = __builtin_bit_cast(u16, hv);
  l = __builtin_bit_cast(u16, lv);
}

// prep_w: W (fp32 [K][256]) -> fp16 hi/lo MFMA-fragment units (proven layout)
__global__ void prep_w(const float* __restrict__ W, int Kact, int nStages,
                       u16* __restrict__ outp){
  int t = blockIdx.x*256 + threadIdx.x;
  if (t >= nStages*1024) return;
  int s = t >> 10, r = t & 1023;
  int w = r >> 8, nf = (r >> 6) & 3, l = r & 63;
  int col = w*64 + nf*16 + (l & 15);
  int kb  = s*32 + (l >> 4)*8;
  u16x8 hv, lv;
  #pragma unroll
  for (int j = 0; j < 8; ++j){
    int k = kb + j;
    float v = (k < Kact) ? W[(size_t)k*HID + col] : 0.f;
    u16 h, lo; split2(v, h, lo);
    hv[j] = h; lv[j] = lo;
  }
  size_t U0 = ((((size_t)s*4 + w)*4 + nf)*2 + 0)*64 + l;
  *(u16x8*)(outp + U0*8)      = hv;
  *(u16x8*)(outp + (U0+64)*8) = lv;
}

// prep_w1c: W1 rows 0..3199 tap-major (step s: tap=s>>2, cg=s&3; k=c*25+tap)
__global__ void prep_w1c(const float* __restrict__ W1, u16* __restrict__ outp){
  int t = blockIdx.x*256 + threadIdx.x;
  if (t >= NS1C*1024) return;
  int s = t >> 10, r = t & 1023;
  int w = r >> 8, nf = (r >> 6) & 3, l = r & 63;
  int col = w*64 + nf*16 + (l & 15);
  int tap = s >> 2, cg = s & 3;
  int cb  = cg*32 + (l >> 4)*8;
  u16x8 hv, lv;
  #pragma unroll
  for (int j = 0; j < 8; ++j){
    int c = cb + j;
    float v = W1[(size_t)(c*25 + tap)*HID + col];
    u16 h, lo; split2(v, h, lo);
    hv[j] = h; lv[j] = lo;
  }
  size_t U0 = ((((size_t)s*4 + w)*4 + nf)*2 + 0)*64 + l;
  *(u16x8*)(outp + U0*8)      = hv;
  *(u16x8*)(outp + (U0+64)*8) = lv;
}

// prep_x: zero-padded channel-interleaved hi/lo planes (r11-proven)
__global__ __launch_bounds__(256)
void prep_x(const float* __restrict__ xi, u16* __restrict__ Xh, u16* __restrict__ Xl){
  int sp = blockIdx.x*256 + threadIdx.x;
  if (sp >= NSP) return;
  int py = sp / SPAD;
  int px = sp - py*SPAD;
  bool inb = (py >= 2) & (py < 258) & (px >= 2) & (px < 258);
  const float* xin = xi + ((size_t)(py-2)<<8) + (px-2);
  #pragma unroll 4
  for (int cg = 0; cg < 16; ++cg){
    u16x8 hv, lv;
    #pragma unroll
    for (int j = 0; j < 8; ++j){
      float v = inb ? xin[((size_t)(cg*8 + j))<<16] : 0.f;
      u16 h, l; split2(v, h, l); hv[j] = h; lv[j] = l;
    }
    *(u16x8*)(Xh + (size_t)sp*128 + cg*8) = hv;
    *(u16x8*)(Xl + (size_t)sp*128 + cg*8) = lv;
  }
}

// ---------------------------------------------------------------------------
// T4 GEMM: 128px x 256col, 512 thr = 8 waves (wave = 64px x 64col, 48 MFMA/step),
// TRIPLE-buffered LDS (3 x 48 KB = 144 KB, 1 block/CU), counted vmcnt(6) +
// raw s_barrier — loads stay in flight across barriers; stage(t+2) issued
// after barrier into the buffer freed at t-1 (2 steps of latency cover).
// Per thread per step: 2 A-DMA + 4 B-DMA (= 6 vmem instr -> vmcnt(6)).
// MODE 0: A = conv taps of Xh/Xl, nt=100, epilogue exact-f32 coords.
// MODE 1: A = Hh/Hl, nt=8. MODE 2: + fused layer-4 tail.
// ---------------------------------------------------------------------------
template<int MODE>
__global__ __launch_bounds__(512, 2)
void gemm(const u16* __restrict__ Ah, const u16* __restrict__ Al,
          const u16* __restrict__ Wp, const float* __restrict__ W1,
          const float* __restrict__ bias, u16* __restrict__ Hh, u16* __restrict__ Hl,
          const float* __restrict__ W4, const float* __restrict__ b4,
          float* __restrict__ out, int nt)
{
  __shared__ __align__(16) u16 Ab[3][8192];    // 16 KB/buf: [mfb(8)][split(2)][unit(64)][8]
  __shared__ __align__(16) u16 Bb[3][16384];   // 32 KB/buf: [g(16)][split(2)][unit(64)][8]

  const int tid  = threadIdx.x;
  const int lane = tid & 63;
  const int wv   = tid >> 6;            // 0..7
  const int wm   = wv >> 2, wn = wv & 3;

  int bid = blockIdx.x;
  bid = (bid & 7)*(NBG/8) + (bid >> 3);   // XCD-chunked swizzle (512%8==0)
  const int pxb = bid * BPXG;
  const int y   = pxb >> 8;
  const int x0  = pxb & 255;              // 0 or 128

  f32x4 acc[4][4];
  #pragma unroll
  for (int a=0;a<4;a++)
    #pragma unroll
    for (int bq=0;bq<4;bq++) acc[a][bq] = f32x4{0.f,0.f,0.f,0.f};

  // A-stage: wave wv owns mfb=wv (px = wv*16+(lane&15)), koct = lane>>4.
  // LDS dest base is wave-uniform (HW adds lane*16) — r11-proven convention.
#define A_STAGE(S, BUF) do { \
    size_t off; \
    if (MODE == 0){ \
      const int tap = (S) >> 2, cg = (S) & 3; \
      const int dy = tap/5, dx = tap - 5*dy; \
      const int sp = (y + dy)*SPAD + (x0 + dx) + wv*16 + (lane & 15); \
      off = (size_t)sp*128 + cg*32 + (lane >> 4)*8; \
    } else { \
      const int px = pxb + wv*16 + (lane & 15); \
      off = (size_t)px*HID + (S)*32 + (lane >> 4)*8; \
    } \
    __builtin_amdgcn_global_load_lds( \
      (const __attribute__((address_space(1))) uint32_t*)(Ah + off), \
      (__attribute__((address_space(3))) uint32_t*)((char*)&Ab[BUF][0] + (wv*2+0)*1024), \
      16, 0, 0); \
    __builtin_amdgcn_global_load_lds( \
      (const __attribute__((address_space(1))) uint32_t*)(Al + off), \
      (__attribute__((address_space(3))) uint32_t*)((char*)&Ab[BUF][0] + (wv*2+1)*1024), \
      16, 0, 0); \
  } while(0)

  // B-stage: 4 instr/thread; wave-uniform LDS base wv*1024 + i*8192.
#define B_STAGE(S, BUF) do { \
    const char* _src = (const char*)Wp + (size_t)(S)*32768 + wv*1024 + lane*16; \
    char* _dst = (char*)&Bb[BUF][0] + wv*1024; \
    _Pragma("unroll") \
    for (int i=0;i<4;++i) \
      __builtin_amdgcn_global_load_lds( \
        (const __attribute__((address_space(1))) uint32_t*)(_src + i*8192), \
        (__attribute__((address_space(3))) uint32_t*)(_dst + i*8192), 16, 0, 0); \
  } while(0)

  // prologue: 2 stages in flight
  A_STAGE(0, 0); B_STAGE(0, 0);
  A_STAGE(1, 1); B_STAGE(1, 1);

  for (int t = 0; t < nt; ++t){
    // counted wait: only stage(t+1)'s 6 vmem instr may remain outstanding
    if (t+1 < nt) { asm volatile("s_waitcnt vmcnt(6)" ::: "memory"); }
    else          { asm volatile("s_waitcnt vmcnt(0)" ::: "memory"); }
    __builtin_amdgcn_s_barrier();          // all waves: buf(t) populated, buf(t-1) reads done
    __builtin_amdgcn_sched_barrier(0);
    if (t+2 < nt){
      const int nb = (t+2) % 3;            // == (t-1)%3, freed by the barrier above
      A_STAGE(t+2, nb);
      B_STAGE(t+2, nb);
    }
    const int cur = t % 3;
    f16x8 ahf[4], alf[4];
    #pragma unroll
    for (int mf=0;mf<4;++mf){
      const int mfb = wm*4 + mf;
      ahf[mf] = *(const f16x8*)(&Ab[cur][((size_t)(mfb*2+0)*64 + lane)*8]);
      alf[mf] = *(const f16x8*)(&Ab[cur][((size_t)(mfb*2+1)*64 + lane)*8]);
    }
    __builtin_amdgcn_s_setprio(1);
    #pragma unroll
    for (int nf=0;nf<4;++nf){
      f16x8 bhv = *(const f16x8*)(&Bb[cur][((size_t)((wn*4+nf)*2+0)*64 + lane)*8]);
      f16x8 blv = *(const f16x8*)(&Bb[cur][((size_t)((wn*4+nf)*2+1)*64 + lane)*8]);
      #pragma unroll
      for (int mf=0;mf<4;++mf){
        acc[mf][nf] = __builtin_amdgcn_mfma_f32_16x16x32_f16(ahf[mf], bhv, acc[mf][nf], 0,0,0);
        acc[mf][nf] = __builtin_amdgcn_mfma_f32_16x16x32_f16(alf[mf], bhv, acc[mf][nf], 0,0,0);
        acc[mf][nf] = __builtin_amdgcn_mfma_f32_16x16x32_f16(ahf[mf], blv, acc[mf][nf], 0,0,0);
      }
    }
    __builtin_amdgcn_s_setprio(0);
  }

  float bcol[4];
  #pragma unroll
  for (int nf=0;nf<4;++nf) bcol[nf] = bias[wn*64 + nf*16 + (lane&15)];

  if (MODE == 0){
    float wyv[4], wxv[4];
    #pragma unroll
    for (int nf=0;nf<4;++nf){
      int col = wn*64 + nf*16 + (lane&15);
      wyv[nf] = W1[(size_t)3200*HID + col];
      wxv[nf] = W1[(size_t)3201*HID + col];
    }
    const float gy = -1.f + (2.f/255.f)*(float)y;
    #pragma unroll
    for (int mf=0;mf<4;++mf)
      #pragma unroll
      for (int nf=0;nf<4;++nf)
        #pragma unroll
        for (int j=0;j<4;++j){
          int row = wm*64 + mf*16 + (lane>>4)*4 + j;          // 0..127
          float gx = -1.f + (2.f/255.f)*(float)(x0 + row);
          float z = acc[mf][nf][j] + bcol[nf] + gy*wyv[nf] + gx*wxv[nf];
          float h = sinf(30.f*z);
          u16 hh,ll; split2(h,hh,ll);
          int col = wn*64 + nf*16 + (lane&15);
          size_t o = (size_t)(pxb+row)*HID + col;
          Hh[o] = hh; Hl[o] = ll;
        }
  } else if (MODE == 1){
    #pragma unroll
    for (int mf=0;mf<4;++mf)
      #pragma unroll
      for (int nf=0;nf<4;++nf)
        #pragma unroll
        for (int j=0;j<4;++j){
          float z = acc[mf][nf][j] + bcol[nf];
          float h = sinf(30.f*z);
          u16 hh,ll; split2(h,hh,ll);
          int row = wm*64 + mf*16 + (lane>>4)*4 + j;
          int col = wn*64 + nf*16 + (lane&15);
          size_t o = (size_t)(pxb+row)*HID + col;
          Hh[o] = hh; Hl[o] = ll;
        }
  } else {
    float (*red)[BPXG][3] = (float(*)[BPXG][3])(void*)&Ab[0][0];  // 12 KB overlay, bufs dead
    float w4v[4][3];
    #pragma unroll
    for (int nf=0;nf<4;++nf){
      int col = wn*64 + nf*16 + (lane&15);
      w4v[nf][0]=W4[col*3+0]; w4v[nf][1]=W4[col*3+1]; w4v[nf][2]=W4[col*3+2];
    }
    #pragma unroll
    for (int mf=0;mf<4;++mf)
      #pragma unroll
      for (int j=0;j<4;++j){
        float s0=0.f,s1=0.f,s2=0.f;
        #pragma unroll
        for (int nf=0;nf<4;++nf){
          float h = sinf(30.f*(acc[mf][nf][j] + bcol[nf]));
          s0 += h*w4v[nf][0]; s1 += h*w4v[nf][1]; s2 += h*w4v[nf][2];
        }
        #pragma unroll
        for (int m=1;m<16;m<<=1){
          s0 += __shfl_xor(s0, m);
          s1 += __shfl_xor(s1, m);
          s2 += __shfl_xor(s2, m);
        }
        if ((lane & 15) == 0){
          int row = wm*64 + mf*16 + (lane>>4)*4 + j;
          red[wv][row][0]=s0; red[wv][row][1]=s1; red[wv][row][2]=s2;
        }
      }
    __syncthreads();
    if (tid < 384){
      int px = tid & 127, c = tid >> 7;
      int wb = (px >> 6)*4;
      float v = red[wb+0][px][c]+red[wb+1][px][c]+red[wb+2][px][c]+red[wb+3][px][c] + b4[c];
      out[(size_t)c*NPX + pxb + px] = v;
    }
  }
#undef A_STAGE
#undef B_STAGE
}

// ---------------------------------------------------------------------------
extern "C" void kernel_launch(void* const* d_in, const int* in_sizes, int n_in,
                              void* d_out, int out_size, void* d_ws, size_t ws_size,
                              hipStream_t stream) {
  const float* xi = (const float*)d_in[0];
  const float* W1 = (const float*)d_in[1];
  const float* b1 = (const float*)d_in[2];
  const float* W2 = (const float*)d_in[3];
  const float* b2 = (const float*)d_in[4];
  const float* W3 = (const float*)d_in[5];
  const float* b3 = (const float*)d_in[6];
  const float* W4 = (const float*)d_in[7];
  const float* b4 = (const float*)d_in[8];
  float* out = (float*)d_out;

  char* ws = (char*)d_ws;
  u16* W1c = (u16*)(ws + OFF_W1C);
  u16* W2p = (u16*)(ws + OFF_W2);
  u16* W3p = (u16*)(ws + OFF_W3);
  u16* Xh  = (u16*)(ws + OFF_XH);
  u16* Xl  = (u16*)(ws + OFF_XL);
  u16* Hh  = (u16*)(ws + OFF_HH);
  u16* Hl  = (u16*)(ws + OFF_HL);

  prep_w1c<<<NS1C*4, 256, 0, stream>>>(W1, W1c);
  prep_w<<<NS2*4, 256, 0, stream>>>(W2, HID, NS2, W2p);
  prep_w<<<NS2*4, 256, 0, stream>>>(W3, HID, NS2, W3p);
  prep_x<<<(NSP + 255)/256, 256, 0, stream>>>(xi, Xh, Xl);

  dim3 grid(NBG), block(512);
  gemm<0><<<grid, block, 0, stream>>>(Xh, Xl, W1c, W1, b1, Hh, Hl,
                                      nullptr, nullptr, nullptr, NS1C);
  gemm<1><<<grid, block, 0, stream>>>(Hh, Hl, W2p, nullptr, b2, Hh, Hl,
                                      nullptr, nullptr, nullptr, NS2);
  gemm<2><<<grid, block, 0, stream>>>(Hh, Hl, W3p, nullptr, b3, nullptr, nullptr,
                                      W4, b4, out, NS2);
}

// Round 13
// 488.775 us; speedup vs baseline: 3.0843x; 1.1512x over previous
//
#include <hip/hip_runtime.h>
#include <math.h>
#include <stdint.h>

typedef _Float16 f16;
typedef _Float16 f16x8 __attribute__((ext_vector_type(8)));
typedef float f32x4 __attribute__((ext_vector_type(4)));
typedef unsigned short u16;
typedef u16 u16x8 __attribute__((ext_vector_type(8)));

#define HID 256
#define NS1C 100              // layer-1 conv K-steps: 25 taps x 4 channel-groups
#define NS2 8                 // 256/32
#define NPX 65536
#define BPXG 256              // pixels per block (one full image row)
#define NBG (NPX/BPXG)        // 256 blocks -> 1 round at 1 block/CU
#define SPAD 260
#define NSP (SPAD*SPAD)

// ws layout (bytes) — same as r12 (~106 MB, fits; proven r9)
#define OFF_W1C 0
#define SZ_W1C  ((size_t)NS1C*32768)
#define OFF_W2  SZ_W1C
#define SZ_W2   ((size_t)NS2*32768)
#define OFF_W3  (OFF_W2+SZ_W2)
#define OFF_XH  ((size_t)4194304)
#define SZ_XP   ((size_t)NSP*128*2)
#define OFF_XL  (OFF_XH + SZ_XP)
#define OFF_HH  (OFF_XL + SZ_XP)
#define SZ_HP   ((size_t)NPX*HID*2)
#define OFF_HL  (OFF_HH + SZ_HP)

__device__ inline void split2(float v, u16& h, u16& l){
  f16 hv = (f16)v;
  f16 lv = (f16)(v - (float)hv);
  h = __builtin_bit_cast(u16, hv);
  l = __builtin_bit_cast(u16, lv);
}

// prep_w: W (fp32 [K][256]) -> fp16 hi/lo MFMA-fragment units (proven layout)
__global__ void prep_w(const float* __restrict__ W, int Kact, int nStages,
                       u16* __restrict__ outp){
  int t = blockIdx.x*256 + threadIdx.x;
  if (t >= nStages*1024) return;
  int s = t >> 10, r = t & 1023;
  int w = r >> 8, nf = (r >> 6) & 3, l = r & 63;
  int col = w*64 + nf*16 + (l & 15);
  int kb  = s*32 + (l >> 4)*8;
  u16x8 hv, lv;
  #pragma unroll
  for (int j = 0; j < 8; ++j){
    int k = kb + j;
    float v = (k < Kact) ? W[(size_t)k*HID + col] : 0.f;
    u16 h, lo; split2(v, h, lo);
    hv[j] = h; lv[j] = lo;
  }
  size_t U0 = ((((size_t)s*4 + w)*4 + nf)*2 + 0)*64 + l;
  *(u16x8*)(outp + U0*8)      = hv;
  *(u16x8*)(outp + (U0+64)*8) = lv;
}

// prep_w1c: W1 rows 0..3199 tap-major (step s: tap=s>>2, cg=s&3; k=c*25+tap)
__global__ void prep_w1c(const float* __restrict__ W1, u16* __restrict__ outp){
  int t = blockIdx.x*256 + threadIdx.x;
  if (t >= NS1C*1024) return;
  int s = t >> 10, r = t & 1023;
  int w = r >> 8, nf = (r >> 6) & 3, l = r & 63;
  int col = w*64 + nf*16 + (l & 15);
  int tap = s >> 2, cg = s & 3;
  int cb  = cg*32 + (l >> 4)*8;
  u16x8 hv, lv;
  #pragma unroll
  for (int j = 0; j < 8; ++j){
    int c = cb + j;
    float v = W1[(size_t)(c*25 + tap)*HID + col];
    u16 h, lo; split2(v, h, lo);
    hv[j] = h; lv[j] = lo;
  }
  size_t U0 = ((((size_t)s*4 + w)*4 + nf)*2 + 0)*64 + l;
  *(u16x8*)(outp + U0*8)      = hv;
  *(u16x8*)(outp + (U0+64)*8) = lv;
}

// prep_x: zero-padded channel-interleaved hi/lo planes (r11-proven)
__global__ __launch_bounds__(256)
void prep_x(const float* __restrict__ xi, u16* __restrict__ Xh, u16* __restrict__ Xl){
  int sp = blockIdx.x*256 + threadIdx.x;
  if (sp >= NSP) return;
  int py = sp / SPAD;
  int px = sp - py*SPAD;
  bool inb = (py >= 2) & (py < 258) & (px >= 2) & (px < 258);
  const float* xin = xi + ((size_t)(py-2)<<8) + (px-2);
  #pragma unroll 4
  for (int cg = 0; cg < 16; ++cg){
    u16x8 hv, lv;
    #pragma unroll
    for (int j = 0; j < 8; ++j){
      float v = inb ? xin[((size_t)(cg*8 + j))<<16] : 0.f;
      u16 h, l; split2(v, h, l); hv[j] = h; lv[j] = l;
    }
    *(u16x8*)(Xh + (size_t)sp*128 + cg*8) = hv;
    *(u16x8*)(Xl + (size_t)sp*128 + cg*8) = lv;
  }
}

// ---------------------------------------------------------------------------
// 256px x 256col GEMM, 512 thr = 8 waves (wave = 128px x 64col, 96 MFMA/step),
// 2-buffer LDS (A 32K + B 32K per buf = 128 KB), counted vmcnt(8) + raw
// barriers. Per step: wait vmcnt(8) [stage(t) done, stage(t+1) in flight] ->
// barrier -> compute -> lgkmcnt(0) -> barrier -> stage(t+2) into freed buffer.
// Per wave per stage: 4 A-DMA + 4 B-DMA = 8 vmem instr -> vmcnt(8).
// MODE 0: A = conv taps of Xh/Xl, nt=100, epilogue exact-f32 coords.
// MODE 1: A = Hh/Hl, nt=8. MODE 2: + fused layer-4 tail.
// ---------------------------------------------------------------------------
template<int MODE>
__global__ __launch_bounds__(512, 2)
void gemm(const u16* __restrict__ Ah, const u16* __restrict__ Al,
          const u16* __restrict__ Wp, const float* __restrict__ W1,
          const float* __restrict__ bias, u16* __restrict__ Hh, u16* __restrict__ Hl,
          const float* __restrict__ W4, const float* __restrict__ b4,
          float* __restrict__ out, int nt)
{
  __shared__ __align__(16) u16 Ab[2][16384];   // 32 KB/buf: [mfb(16)][split(2)][unit(64)][8]
  __shared__ __align__(16) u16 Bb[2][16384];   // 32 KB/buf: [g(16)][split(2)][unit(64)][8]

  const int tid  = threadIdx.x;
  const int lane = tid & 63;
  const int wv   = tid >> 6;            // 0..7
  const int wm   = wv >> 2, wn = wv & 3;

  int bid = blockIdx.x;
  bid = (bid & 7)*(NBG/8) + (bid >> 3);   // XCD-chunked swizzle (256%8==0)
  const int pxb = bid * BPXG;             // one full image row
  const int y   = bid;                    // row index

  f32x4 acc[8][4];
  #pragma unroll
  for (int a=0;a<8;a++)
    #pragma unroll
    for (int bq=0;bq<4;bq++) acc[a][bq] = f32x4{0.f,0.f,0.f,0.f};

  // A-stage: wave wv stages mfb = wv*2+u (u=0,1), hi+lo -> 4 DMA/wave.
  // px = mfb*16 + (lane&15), k-octet = lane>>4. LDS dest wave-uniform base.
#define A_STAGE(S, BUF) do { \
    _Pragma("unroll") \
    for (int u=0;u<2;++u){ \
      const int mfb = wv*2 + u; \
      size_t off; \
      if (MODE == 0){ \
        const int tap = (S) >> 2, cg = (S) & 3; \
        const int dy = tap/5, dx = tap - 5*dy; \
        const int sp = (y + dy)*SPAD + dx + mfb*16 + (lane & 15); \
        off = (size_t)sp*128 + cg*32 + (lane >> 4)*8; \
      } else { \
        const int px = pxb + mfb*16 + (lane & 15); \
        off = (size_t)px*HID + (S)*32 + (lane >> 4)*8; \
      } \
      __builtin_amdgcn_global_load_lds( \
        (const __attribute__((address_space(1))) uint32_t*)(Ah + off), \
        (__attribute__((address_space(3))) uint32_t*)((char*)&Ab[BUF][0] + (mfb*2+0)*1024), \
        16, 0, 0); \
      __builtin_amdgcn_global_load_lds( \
        (const __attribute__((address_space(1))) uint32_t*)(Al + off), \
        (__attribute__((address_space(3))) uint32_t*)((char*)&Ab[BUF][0] + (mfb*2+1)*1024), \
        16, 0, 0); \
    } \
  } while(0)

  // B-stage: linear 32 KB slab copy; wave wv covers [wv*4096, +4096) -> 4 DMA.
#define B_STAGE(S, BUF) do { \
    const char* _src = (const char*)Wp + (size_t)(S)*32768 + wv*4096 + lane*16; \
    char* _dst = (char*)&Bb[BUF][0] + wv*4096; \
    _Pragma("unroll") \
    for (int i=0;i<4;++i) \
      __builtin_amdgcn_global_load_lds( \
        (const __attribute__((address_space(1))) uint32_t*)(_src + i*1024), \
        (__attribute__((address_space(3))) uint32_t*)(_dst + i*1024), 16, 0, 0); \
  } while(0)

  // prologue: 2 stages in flight
  A_STAGE(0, 0); B_STAGE(0, 0);
  A_STAGE(1, 1); B_STAGE(1, 1);

  for (int t = 0; t < nt; ++t){
    // counted wait: only stage(t+1)'s 8 vmem instr may remain outstanding
    if (t+1 < nt) { asm volatile("s_waitcnt vmcnt(8)" ::: "memory"); }
    else          { asm volatile("s_waitcnt vmcnt(0)" ::: "memory"); }
    __builtin_amdgcn_s_barrier();          // buf(t&1) fully staged (all waves)
    __builtin_amdgcn_sched_barrier(0);
    const int cur = t & 1;

    f16x8 bh[4], bl[4];
    #pragma unroll
    for (int nf=0;nf<4;++nf){
      bh[nf] = *(const f16x8*)(&Bb[cur][((size_t)((wn*4+nf)*2+0)*64 + lane)*8]);
      bl[nf] = *(const f16x8*)(&Bb[cur][((size_t)((wn*4+nf)*2+1)*64 + lane)*8]);
    }
    __builtin_amdgcn_s_setprio(1);
    #pragma unroll
    for (int mf=0;mf<8;++mf){
      const int mfb = wm*8 + mf;
      f16x8 ahf = *(const f16x8*)(&Ab[cur][((size_t)(mfb*2+0)*64 + lane)*8]);
      f16x8 alf = *(const f16x8*)(&Ab[cur][((size_t)(mfb*2+1)*64 + lane)*8]);
      #pragma unroll
      for (int nf=0;nf<4;++nf){
        acc[mf][nf] = __builtin_amdgcn_mfma_f32_16x16x32_f16(ahf, bh[nf], acc[mf][nf], 0,0,0);
        acc[mf][nf] = __builtin_amdgcn_mfma_f32_16x16x32_f16(alf, bh[nf], acc[mf][nf], 0,0,0);
        acc[mf][nf] = __builtin_amdgcn_mfma_f32_16x16x32_f16(ahf, bl[nf], acc[mf][nf], 0,0,0);
      }
    }
    __builtin_amdgcn_s_setprio(0);
    asm volatile("s_waitcnt lgkmcnt(0)" ::: "memory");  // all my ds_reads retired
    __builtin_amdgcn_s_barrier();          // all waves done reading buf(cur)
    if (t+2 < nt){
      A_STAGE(t+2, cur);                   // refill the buffer just consumed
      B_STAGE(t+2, cur);
    }
  }

  float bcol[4];
  #pragma unroll
  for (int nf=0;nf<4;++nf) bcol[nf] = bias[wn*64 + nf*16 + (lane&15)];

  if (MODE == 0){
    float wyv[4], wxv[4];
    #pragma unroll
    for (int nf=0;nf<4;++nf){
      int col = wn*64 + nf*16 + (lane&15);
      wyv[nf] = W1[(size_t)3200*HID + col];
      wxv[nf] = W1[(size_t)3201*HID + col];
    }
    const float gy = -1.f + (2.f/255.f)*(float)y;
    #pragma unroll
    for (int mf=0;mf<8;++mf)
      #pragma unroll
      for (int nf=0;nf<4;++nf)
        #pragma unroll
        for (int j=0;j<4;++j){
          int row = wm*128 + mf*16 + (lane>>4)*4 + j;          // 0..255 = x coord
          float gx = -1.f + (2.f/255.f)*(float)row;
          float z = acc[mf][nf][j] + bcol[nf] + gy*wyv[nf] + gx*wxv[nf];
          float h = sinf(30.f*z);
          u16 hh,ll; split2(h,hh,ll);
          int col = wn*64 + nf*16 + (lane&15);
          size_t o = (size_t)(pxb+row)*HID + col;
          Hh[o] = hh; Hl[o] = ll;
        }
  } else if (MODE == 1){
    #pragma unroll
    for (int mf=0;mf<8;++mf)
      #pragma unroll
      for (int nf=0;nf<4;++nf)
        #pragma unroll
        for (int j=0;j<4;++j){
          float z = acc[mf][nf][j] + bcol[nf];
          float h = sinf(30.f*z);
          u16 hh,ll; split2(h,hh,ll);
          int row = wm*128 + mf*16 + (lane>>4)*4 + j;
          int col = wn*64 + nf*16 + (lane&15);
          size_t o = (size_t)(pxb+row)*HID + col;
          Hh[o] = hh; Hl[o] = ll;
        }
  } else {
    float (*red)[BPXG][3] = (float(*)[BPXG][3])(void*)&Ab[0][0];  // 24 KB overlay, bufs dead
    float w4v[4][3];
    #pragma unroll
    for (int nf=0;nf<4;++nf){
      int col = wn*64 + nf*16 + (lane&15);
      w4v[nf][0]=W4[col*3+0]; w4v[nf][1]=W4[col*3+1]; w4v[nf][2]=W4[col*3+2];
    }
    #pragma unroll
    for (int mf=0;mf<8;++mf)
      #pragma unroll
      for (int j=0;j<4;++j){
        float s0=0.f,s1=0.f,s2=0.f;
        #pragma unroll
        for (int nf=0;nf<4;++nf){
          float h = sinf(30.f*(acc[mf][nf][j] + bcol[nf]));
          s0 += h*w4v[nf][0]; s1 += h*w4v[nf][1]; s2 += h*w4v[nf][2];
        }
        #pragma unroll
        for (int m=1;m<16;m<<=1){
          s0 += __shfl_xor(s0, m);
          s1 += __shfl_xor(s1, m);
          s2 += __shfl_xor(s2, m);
        }
        if ((lane & 15) == 0){
          int row = wm*128 + mf*16 + (lane>>4)*4 + j;
          red[wn + wm*4][row][0]=s0; red[wn + wm*4][row][1]=s1; red[wn + wm*4][row][2]=s2;
        }
      }
    __syncthreads();
    for (int o = tid; o < BPXG*3; o += 512){
      int px = o & 255, c = o >> 8;
      int wb = (px >> 7)*4;    // waves with wm = px>>7 hold this row
      float v = red[wb+0][px][c]+red[wb+1][px][c]+red[wb+2][px][c]+red[wb+3][px][c] + b4[c];
      out[(size_t)c*NPX + pxb + px] = v;
    }
  }
#undef A_STAGE
#undef B_STAGE
}

// ---------------------------------------------------------------------------
extern "C" void kernel_launch(void* const* d_in, const int* in_sizes, int n_in,
                              void* d_out, int out_size, void* d_ws, size_t ws_size,
                              hipStream_t stream) {
  const float* xi = (const float*)d_in[0];
  const float* W1 = (const float*)d_in[1];
  const float* b1 = (const float*)d_in[2];
  const float* W2 = (const float*)d_in[3];
  const float* b2 = (const float*)d_in[4];
  const float* W3 = (const float*)d_in[5];
  const float* b3 = (const float*)d_in[6];
  const float* W4 = (const float*)d_in[7];
  const float* b4 = (const float*)d_in[8];
  float* out = (float*)d_out;

  char* ws = (char*)d_ws;
  u16* W1c = (u16*)(ws + OFF_W1C);
  u16* W2p = (u16*)(ws + OFF_W2);
  u16* W3p = (u16*)(ws + OFF_W3);
  u16* Xh  = (u16*)(ws + OFF_XH);
  u16* Xl  = (u16*)(ws + OFF_XL);
  u16* Hh  = (u16*)(ws + OFF_HH);
  u16* Hl  = (u16*)(ws + OFF_HL);

  prep_w1c<<<NS1C*4, 256, 0, stream>>>(W1, W1c);
  prep_w<<<NS2*4, 256, 0, stream>>>(W2, HID, NS2, W2p);
  prep_w<<<NS2*4, 256, 0, stream>>>(W3, HID, NS2, W3p);
  prep_x<<<(NSP + 255)/256, 256, 0, stream>>>(xi, Xh, Xl);

  dim3 grid(NBG), block(512);
  gemm<0><<<grid, block, 0, stream>>>(Xh, Xl, W1c, W1, b1, Hh, Hl,
                                      nullptr, nullptr, nullptr, NS1C);
  gemm<1><<<grid, block, 0, stream>>>(Hh, Hl, W2p, nullptr, b2, Hh, Hl,
                                      nullptr, nullptr, nullptr, NS2);
  gemm<2><<<grid, block, 0, stream>>>(Hh, Hl, W3p, nullptr, b3, nullptr, nullptr,
                                      W4, b4, out, NS2);
}